// Round 3
// baseline (2076.073 us; speedup 1.0000x reference)
//
#include <hip/hip_runtime.h>
#include <hip/hip_bf16.h>
#include <cstdio>

#define N_NODES 100000
#define E_EDGES 3200000
#define N_GRAPH 512
#define HDIM 64
#define BN_EPS 1e-5f
#define NBUCKET ((N_NODES + 255) / 256)   // 391
#define SORT_CAP 12288                    // entries per bucket LDS (mean 8192, sd ~90)

// ---------------- degree count ----------------

__global__ void count_k(const int* __restrict__ dst, int* __restrict__ deg) {
    int e = blockIdx.x * 256 + threadIdx.x;
    if (e < E_EDGES) atomicAdd(&deg[dst[e]], 1);
}

// dinv + pre-scaled layer-1 input (xtil = dinv * x)
__global__ void dinv_k(const int* __restrict__ deg, const float* __restrict__ x,
                       float* __restrict__ dinv, float* __restrict__ xtil) {
    int v = blockIdx.x * 256 + threadIdx.x;
    if (v >= N_NODES) return;
    float dv = rsqrtf((float)(deg[v] + 1));
    dinv[v] = dv;
    xtil[v] = dv * x[v];
}

// ---------------- scan (node degrees -> ptr) ----------------

__global__ void scan1_k(const int* __restrict__ deg, int* __restrict__ ptr,
                        int* __restrict__ bsum) {
    __shared__ int sh[256];
    int t = threadIdx.x;
    int i = blockIdx.x * 256 + t;
    int v = (i < N_NODES) ? deg[i] : 0;
    sh[t] = v;
    __syncthreads();
    for (int off = 1; off < 256; off <<= 1) {
        int add = (t >= off) ? sh[t - off] : 0;
        __syncthreads();
        sh[t] += add;
        __syncthreads();
    }
    if (i < N_NODES) ptr[i] = sh[t] - v;
    if (t == 255) bsum[blockIdx.x] = sh[255];
}

__global__ void scan2_k(int* __restrict__ bsum, int nb) {
    __shared__ int sh[512];
    int t = threadIdx.x;
    int v = (t < nb) ? bsum[t] : 0;
    sh[t] = v;
    __syncthreads();
    for (int off = 1; off < 512; off <<= 1) {
        int add = (t >= off) ? sh[t - off] : 0;
        __syncthreads();
        sh[t] += add;
        __syncthreads();
    }
    if (t < nb) bsum[t] = sh[t] - v;
}

__global__ void scan3_k(int* __restrict__ ptr, const int* __restrict__ bsum,
                        int* __restrict__ btail) {
    int i = blockIdx.x * 256 + threadIdx.x;
    if (i < N_NODES) {
        int p = ptr[i] + bsum[i >> 8];
        ptr[i] = p;
        if ((i & 255) == 0) btail[i >> 8] = p;  // bucket tail starts at ptr[256b]
    }
    if (i == 0) ptr[N_NODES] = E_EDGES;
}

// ---------------- fill: scatter 4B packed entries into 391 bucket regions ----------------
// packed = u | ((dst&255)<<17); bucket = dst>>8. Tail lines are L2-hot -> ~streaming writes.

__global__ void fill_direct_k(const int* __restrict__ src, const int* __restrict__ dst,
                              int* __restrict__ btail, int* __restrict__ staging) {
    int e = blockIdx.x * 256 + threadIdx.x;
    if (e >= E_EDGES) return;
    int v = dst[e];
    int u = src[e];
    int pos = atomicAdd(&btail[v >> 8], 1);
    staging[pos] = u | ((v & 255) << 17);
}

// ---------------- per-bucket sort -> final CSR (u only) + fused layer-1 scalar agg ----
// Block b owns nodes [256b, 256b+256). All their edges are in staging[ptr[256b]..).

__global__ __launch_bounds__(256) void sort_bucket_k(
    const int* __restrict__ staging, const int* __restrict__ ptr,
    const float* __restrict__ dinv, const float* __restrict__ xtil,
    const float* __restrict__ x, int* __restrict__ csr, float* __restrict__ sfull) {
    __shared__ int lbase[257];
    __shared__ int lcnt[256];
    __shared__ int lds_u[SORT_CAP];
    int t = threadIdx.x;
    int v0 = blockIdx.x << 8;
    int p0 = ptr[v0];
    for (int i = t; i < 257; i += 256) {
        int vv = v0 + i;
        lbase[i] = ptr[(vv < N_NODES) ? vv : N_NODES] - p0;
    }
    lcnt[t] = 0;
    __syncthreads();
    int cnt = lbase[256];

    for (int i = t; i < cnt; i += 256) {
        int packed = staging[p0 + i];         // coalesced
        int u = packed & 0x1FFFF;
        int vl = packed >> 17;
        int r = atomicAdd(&lcnt[vl], 1);      // LDS atomic
        int pos = lbase[vl] + r;
        if (pos < SORT_CAP) lds_u[pos] = u;
        else csr[p0 + pos] = u;               // overflow fallback (never at this scale)
    }
    __syncthreads();
    int lim = (cnt < SORT_CAP) ? cnt : SORT_CAP;
    for (int i = t; i < lim; i += 256) csr[p0 + i] = lds_u[i]; // coalesced

    __syncthreads();
    // layer 1 (rank-1): sfull[v] = dv * sum(xtil[u]) + dv^2 * x[v]
    int v = v0 + t;
    if (v < N_NODES) {
        int j0 = lbase[t], j1 = lbase[t + 1];
        float s = 0.f;
        for (int j = j0; j < j1; j++) {
            int u = (j < SORT_CAP) ? lds_u[j] : csr[p0 + j];
            s += xtil[u];                     // 4B gather from 400KB L2-resident table
        }
        float dv = dinv[v];
        sfull[v] = dv * s + dv * dv * x[v];
    }
}

// layer 1 expand: x1til[v,f] = dinv[v] * relu(bn(sfull[v]*w1[f]+b1[f]))
__global__ void l1_expand_k(const float* __restrict__ sfull, const float* __restrict__ dinv,
                            const float* __restrict__ w1, const float* __restrict__ b1,
                            const float* __restrict__ bg, const float* __restrict__ bb,
                            const float* __restrict__ brm, const float* __restrict__ brv,
                            float* __restrict__ xout) {
    int tid = blockIdx.x * 256 + threadIdx.x;
    if (tid >= N_NODES * HDIM) return;
    int v = tid >> 6;
    int f = tid & 63;
    float sc = bg[f] * rsqrtf(brv[f] + BN_EPS);
    float val = (sfull[v] * w1[f] + b1[f] - brm[f]) * sc + bb[f];
    xout[tid] = dinv[v] * fmaxf(val, 0.f);
}

// ---------------- Layers 2/3 ----------------
// xin rows are pre-scaled by dinv[u]: agg[v] = dv*(sum_{u in N(v)} xin[u] + xin[v]).
// Wave per node; quarter q handles edge e+q; lane loads float4 (16 lanes = 256B row).
// Unroll 4 -> up to 4 row gathers in flight. Epilogue: @W via readlane + BN + ReLU,
// output optionally pre-scaled by dinv for the next layer.

__global__ __launch_bounds__(256) void agg_gemm_k(
    const float* __restrict__ xin, float* __restrict__ xout,
    const int* __restrict__ ptr, const int* __restrict__ csr,
    const float* __restrict__ dinv, const float* __restrict__ oscale_arr,
    const float* __restrict__ W, const float* __restrict__ bias,
    const float* __restrict__ bg, const float* __restrict__ bb,
    const float* __restrict__ brm, const float* __restrict__ brv) {
    __shared__ float wsh[HDIM * HDIM]; // 16 KB
    __shared__ float sM[HDIM], sC[HDIM];
    int tid = threadIdx.x;
    for (int i = tid; i < HDIM * HDIM; i += 256) wsh[i] = W[i];
    if (tid < HDIM) {
        float sc = bg[tid] * rsqrtf(brv[tid] + BN_EPS);
        sM[tid] = sc;
        sC[tid] = (bias[tid] - brm[tid]) * sc + bb[tid];
    }
    __syncthreads();

    int lane = tid & 63;
    int v = (blockIdx.x << 2) + (tid >> 6);
    if (v >= N_NODES) return;
    int q = lane >> 4;
    int s = lane & 15;

    const float4* __restrict__ xin4 = (const float4*)xin;
    int e0 = ptr[v], e1 = ptr[v + 1];
    float4 acc;
    { // self-loop: add own (pre-scaled) row once (quarter 0)
        if (q == 0) {
            acc = xin4[(size_t)v * 16 + s];
        } else {
            acc.x = acc.y = acc.z = acc.w = 0.f;
        }
    }

    for (int e = e0; e < e1; e += 16) {
#pragma unroll
        for (int j = 0; j < 4; j++) {
            int ee = e + j * 4 + q;
            if (ee < e1) {
                int u = csr[ee];                         // 4B, broadcast in quarter
                float4 row = xin4[(size_t)u * 16 + s];   // coalesced 16B/lane
                acc.x += row.x; acc.y += row.y;
                acc.z += row.z; acc.w += row.w;
            }
        }
    }

    float a4[4] = {acc.x, acc.y, acc.z, acc.w};
#pragma unroll
    for (int i = 0; i < 4; i++) {
        a4[i] += __shfl_xor(a4[i], 16);
        a4[i] += __shfl_xor(a4[i], 32);
    }

    int f = lane;
    float o = 0.f;
#pragma unroll
    for (int k = 0; k < HDIM; k++) {
        float a = __shfl(a4[k & 3], k >> 2);
        o += a * wsh[(k << 6) + f];
    }
    float dv = dinv[v];
    float osc = oscale_arr ? oscale_arr[v] : 1.f;
    float val = fmaxf(dv * o * sM[f] + sC[f], 0.f);
    xout[(size_t)v * HDIM + f] = osc * val;
}

// ---------------- Pool (mean/max per graph) + MLP head ----------------

__device__ inline int lower_bound_i(const int* __restrict__ a, int n, int val) {
    int lo = 0, hi = n;
    while (lo < hi) {
        int mid = (lo + hi) >> 1;
        if (a[mid] < val) lo = mid + 1; else hi = mid;
    }
    return lo;
}

__global__ void pool_mlp_k(const float* __restrict__ x, const int* __restrict__ batch,
                           const float* __restrict__ wl1, const float* __restrict__ bl1,
                           const float* __restrict__ wl2, const float* __restrict__ bl2,
                           const float* __restrict__ bg, const float* __restrict__ bb,
                           const float* __restrict__ brm, const float* __restrict__ brv,
                           float* __restrict__ out) {
    int g = blockIdx.x;
    int tid = threadIdx.x;
    int w = tid >> 6;
    int f = tid & 63;
    int start = lower_bound_i(batch, N_NODES, g);
    int end = lower_bound_i(batch, N_NODES, g + 1);
    float sum = 0.f;
    float mx = -3.402823466e38f;
#pragma unroll 2
    for (int v = start + w; v < end; v += 4) {
        float val = x[(size_t)v * HDIM + f];
        sum += val;
        mx = fmaxf(mx, val);
    }
    __shared__ float ssum[4][HDIM], smax[4][HDIM];
    __shared__ float zs[2 * HDIM];
    ssum[w][f] = sum;
    smax[w][f] = mx;
    __syncthreads();
    if (tid < 64) {
        float sm = ssum[0][f] + ssum[1][f] + ssum[2][f] + ssum[3][f];
        float m = fmaxf(fmaxf(smax[0][f], smax[1][f]), fmaxf(smax[2][f], smax[3][f]));
        float cnt = (float)(end - start);
        zs[f] = sm / fmaxf(cnt, 1.f);
        zs[HDIM + f] = m;
    }
    __syncthreads();
    if (tid >= 64) return;

    float o = bl1[f];
#pragma unroll 8
    for (int k = 0; k < 2 * HDIM; k++) {
        o += zs[k] * wl1[k * HDIM + f];
    }
    float sc = bg[f] * rsqrtf(brv[f] + BN_EPS);
    o = fmaxf((o - brm[f]) * sc + bb[f], 0.f);

    float p0 = o * wl2[f * 2 + 0];
    float p1 = o * wl2[f * 2 + 1];
    for (int off = 32; off > 0; off >>= 1) {
        p0 += __shfl_down(p0, off);
        p1 += __shfl_down(p1, off);
    }
    if (f == 0) {
        out[g * 2 + 0] = p0 + bl2[0];
        out[g * 2 + 1] = p1 + bl2[1];
    }
}

// ---------------- launch ----------------

extern "C" void kernel_launch(void* const* d_in, const int* in_sizes, int n_in,
                              void* d_out, int out_size, void* d_ws, size_t ws_size,
                              hipStream_t stream) {
    const float* x    = (const float*)d_in[0];
    const int* src    = (const int*)d_in[1];
    const int* dst    = (const int*)d_in[2];
    const int* batch  = (const int*)d_in[3];
    const float* w1   = (const float*)d_in[4];
    const float* b1   = (const float*)d_in[5];
    const float* w2   = (const float*)d_in[6];
    const float* b2   = (const float*)d_in[7];
    const float* w3   = (const float*)d_in[8];
    const float* b3   = (const float*)d_in[9];
    const float* wl1  = (const float*)d_in[10];
    const float* bl1  = (const float*)d_in[11];
    const float* wl2  = (const float*)d_in[12];
    const float* bl2  = (const float*)d_in[13];
    const float* bn1g = (const float*)d_in[14];
    const float* bn1b = (const float*)d_in[15];
    const float* bn1rm = (const float*)d_in[16];
    const float* bn1rv = (const float*)d_in[17];
    const float* bn2g = (const float*)d_in[18];
    const float* bn2b = (const float*)d_in[19];
    const float* bn2rm = (const float*)d_in[20];
    const float* bn2rv = (const float*)d_in[21];
    const float* bn3g = (const float*)d_in[22];
    const float* bn3b = (const float*)d_in[23];
    const float* bn3rm = (const float*)d_in[24];
    const float* bn3rv = (const float*)d_in[25];
    const float* bnlg = (const float*)d_in[26];
    const float* bnlb = (const float*)d_in[27];
    const float* bnlrm = (const float*)d_in[28];
    const float* bnlrv = (const float*)d_in[29];
    float* out = (float*)d_out;

    char* ws = (char*)d_ws;
    size_t off = 0;
    auto alloc = [&](size_t bytes) -> char* {
        off = (off + 255) & ~(size_t)255;
        char* p = ws + off;
        off += bytes;
        return p;
    };
    int*   deg_i   = (int*)alloc((size_t)N_NODES * 4);
    float* dinv    = (float*)alloc((size_t)N_NODES * 4);
    float* xtil    = (float*)alloc((size_t)N_NODES * 4);
    int*   ptr     = (int*)alloc(((size_t)N_NODES + 1) * 4);
    int*   bsum    = (int*)alloc(1024 * 4);
    int*   btail   = (int*)alloc(NBUCKET * 4);
    int*   staging = (int*)alloc((size_t)E_EDGES * 4);
    int*   csr     = (int*)alloc((size_t)E_EDGES * 4);
    float* sfull   = (float*)alloc((size_t)N_NODES * 4);
    float* xa      = (float*)alloc((size_t)N_NODES * HDIM * 4);
    float* xb      = (float*)alloc((size_t)N_NODES * HDIM * 4);
    if (off > ws_size) {
        fprintf(stderr, "kernel_launch: ws too small (%zu > %zu)\n", off, ws_size);
    }

    const int NB_N  = (N_NODES + 255) / 256;
    const int NB_E  = (E_EDGES + 255) / 256;
    const int NB_NH = (N_NODES * HDIM + 255) / 256;
    const int NB_WV = (N_NODES + 3) / 4;

    hipMemsetAsync(deg_i, 0, (size_t)N_NODES * 4, stream);

    count_k<<<NB_E, 256, 0, stream>>>(dst, deg_i);
    dinv_k<<<NB_N, 256, 0, stream>>>(deg_i, x, dinv, xtil);
    scan1_k<<<NB_N, 256, 0, stream>>>(deg_i, ptr, bsum);
    scan2_k<<<1, 512, 0, stream>>>(bsum, NB_N);
    scan3_k<<<NB_N, 256, 0, stream>>>(ptr, bsum, btail);
    fill_direct_k<<<NB_E, 256, 0, stream>>>(src, dst, btail, staging);
    sort_bucket_k<<<NBUCKET, 256, 0, stream>>>(staging, ptr, dinv, xtil, x, csr, sfull);

    l1_expand_k<<<NB_NH, 256, 0, stream>>>(sfull, dinv, w1, b1,
                                           bn1g, bn1b, bn1rm, bn1rv, xa);

    agg_gemm_k<<<NB_WV, 256, 0, stream>>>(xa, xb, ptr, csr, dinv, dinv,
                                          w2, b2, bn2g, bn2b, bn2rm, bn2rv);
    agg_gemm_k<<<NB_WV, 256, 0, stream>>>(xb, xa, ptr, csr, dinv, nullptr,
                                          w3, b3, bn3g, bn3b, bn3rm, bn3rv);

    pool_mlp_k<<<N_GRAPH, 256, 0, stream>>>(xa, batch, wl1, bl1, wl2, bl2,
                                            bnlg, bnlb, bnlrm, bnlrv, out);
}

// Round 4
// 887.623 us; speedup vs baseline: 2.3389x; 2.3389x over previous
//
#include <hip/hip_runtime.h>
#include <hip/hip_bf16.h>
#include <cstdio>

#define N_NODES 100000
#define E_EDGES 3200000
#define N_GRAPH 512
#define HDIM 64
#define BN_EPS 1e-5f
#define NBUCKET ((N_NODES + 255) / 256)   // 391 buckets of 256 nodes
#define NCHUNK 256                        // edge chunks (radix partition)
#define CHUNK ((E_EDGES + NCHUNK - 1) / NCHUNK) // 12500 edges/chunk
#define SORT_CAP 12288                    // per-bucket LDS entries (mean 8192, max ~8600)

// ======== counter-free radix partition of edges by dst>>8 ========

// per-chunk bucket histogram (LDS atomics only)
__global__ __launch_bounds__(256) void hist_k(const int* __restrict__ dst,
                                              int* __restrict__ histT) {
    __shared__ int h[NBUCKET];
    int c = blockIdx.x, t = threadIdx.x;
    for (int i = t; i < NBUCKET; i += 256) h[i] = 0;
    __syncthreads();
    int e0 = c * CHUNK;
    int e1 = min(e0 + CHUNK, E_EDGES);
    for (int e = e0 + t; e < e1; e += 256)
        atomicAdd(&h[dst[e] >> 8], 1);
    __syncthreads();
    for (int i = t; i < NBUCKET; i += 256) histT[i * NCHUNK + c] = h[i];
}

// bucket totals + exclusive scan across buckets -> bucket_base
__global__ void scanA_k(const int* __restrict__ histT, int* __restrict__ bucket_base) {
    __shared__ int sh[512];
    int t = threadIdx.x;
    int sum = 0;
    if (t < NBUCKET) {
        const int* row = histT + t * NCHUNK;
        for (int c = 0; c < NCHUNK; c++) sum += row[c];
    }
    sh[t] = sum;
    __syncthreads();
    for (int off = 1; off < 512; off <<= 1) {
        int add = (t >= off) ? sh[t - off] : 0;
        __syncthreads();
        sh[t] += add;
        __syncthreads();
    }
    if (t < NBUCKET) bucket_base[t] = sh[t] - sum;
    if (t == 0) bucket_base[NBUCKET] = E_EDGES;
}

// per-bucket exclusive scan across chunks -> scannedT[b][c] = global write base
__global__ __launch_bounds__(NCHUNK) void scanB_k(const int* __restrict__ histT,
                                                  const int* __restrict__ bucket_base,
                                                  int* __restrict__ scannedT) {
    __shared__ int sh[NCHUNK];
    int b = blockIdx.x, t = threadIdx.x;
    int v = histT[b * NCHUNK + t];
    sh[t] = v;
    __syncthreads();
    for (int off = 1; off < NCHUNK; off <<= 1) {
        int add = (t >= off) ? sh[t - off] : 0;
        __syncthreads();
        sh[t] += add;
        __syncthreads();
    }
    scannedT[b * NCHUNK + t] = bucket_base[b] + sh[t] - v;
}

// scatter: exact positions, LDS atomics only for within-(chunk,bucket) rank
__global__ __launch_bounds__(256) void scatter_k(const int* __restrict__ src,
                                                 const int* __restrict__ dst,
                                                 const int* __restrict__ scannedT,
                                                 int* __restrict__ staging) {
    __shared__ int lcnt[NBUCKET];
    int c = blockIdx.x, t = threadIdx.x;
    for (int i = t; i < NBUCKET; i += 256) lcnt[i] = scannedT[i * NCHUNK + c];
    __syncthreads();
    int e0 = c * CHUNK;
    int e1 = min(e0 + CHUNK, E_EDGES);
    for (int e = e0 + t; e < e1; e += 256) {
        int v = dst[e], u = src[e];
        int pos = atomicAdd(&lcnt[v >> 8], 1);       // LDS atomic, mean 32/bucket
        staging[pos] = u | ((v & 255) << 17);        // 4B, ~128B runs per bucket
    }
}

// ======== per-bucket: node degrees -> ptr/dinv/xtil (no global node scan) ========

__global__ __launch_bounds__(256) void nodeptr_k(const int* __restrict__ staging,
                                                 const int* __restrict__ bucket_base,
                                                 const float* __restrict__ x,
                                                 int* __restrict__ ptr,
                                                 float* __restrict__ dinv,
                                                 float* __restrict__ xtil) {
    __shared__ int hn[256];
    __shared__ int sc[256];
    int t = threadIdx.x, b = blockIdx.x;
    int v0 = b << 8;
    int p0 = bucket_base[b], p1 = bucket_base[b + 1];
    hn[t] = 0;
    __syncthreads();
    int cnt = p1 - p0;
    for (int i = t; i < cnt; i += 256)
        atomicAdd(&hn[staging[p0 + i] >> 17], 1);
    __syncthreads();
    int my = hn[t];
    sc[t] = my;
    __syncthreads();
    for (int off = 1; off < 256; off <<= 1) {
        int add = (t >= off) ? sc[t - off] : 0;
        __syncthreads();
        sc[t] += add;
        __syncthreads();
    }
    int v = v0 + t;
    if (v < N_NODES) {
        ptr[v] = p0 + sc[t] - my;                // exclusive
        float dv = rsqrtf((float)(my + 1));      // deg + self-loop
        dinv[v] = dv;
        xtil[v] = dv * x[v];
    }
    if (b == NBUCKET - 1 && t == 0) ptr[N_NODES] = E_EDGES;
}

// ======== per-bucket: grouped CSR write + fused layer-1 scalar aggregation ========

__global__ __launch_bounds__(256) void csr_l1_k(const int* __restrict__ staging,
                                                const int* __restrict__ ptr,
                                                const int* __restrict__ bucket_base,
                                                const float* __restrict__ dinv,
                                                const float* __restrict__ xtil,
                                                const float* __restrict__ x,
                                                int* __restrict__ csr,
                                                float* __restrict__ sfull) {
    __shared__ int lbase[257];
    __shared__ int lcnt[256];
    __shared__ int lds_u[SORT_CAP];
    int t = threadIdx.x, b = blockIdx.x;
    int v0 = b << 8;
    int p0 = bucket_base[b];
    for (int i = t; i < 257; i += 256) {
        int vv = v0 + i;
        lbase[i] = ((vv < N_NODES) ? ptr[vv] : E_EDGES) - p0;
    }
    lcnt[t] = 0;
    __syncthreads();
    int cnt = lbase[256];
    for (int i = t; i < cnt; i += 256) {
        int packed = staging[p0 + i];          // coalesced
        int u = packed & 0x1FFFF;
        int vl = packed >> 17;
        int r = atomicAdd(&lcnt[vl], 1);       // LDS atomic
        int pos = lbase[vl] + r;
        if (pos < SORT_CAP) lds_u[pos] = u;
        else csr[p0 + pos] = u;                // overflow fallback
    }
    __syncthreads();
    int lim = (cnt < SORT_CAP) ? cnt : SORT_CAP;
    for (int i = t; i < lim; i += 256) csr[p0 + i] = lds_u[i]; // coalesced
    __syncthreads();
    // layer 1 (rank-1): sfull[v] = dv * sum(xtil[u]) + dv^2 * x[v]
    int v = v0 + t;
    if (v < N_NODES) {
        int j0 = lbase[t], j1 = lbase[t + 1];
        float s = 0.f;
        for (int j = j0; j < j1; j++) {
            int u = (j < SORT_CAP) ? lds_u[j] : csr[p0 + j];
            s += xtil[u];                       // 400KB L2-resident table
        }
        float dv = dinv[v];
        sfull[v] = dv * s + dv * dv * x[v];
    }
}

// layer 1 expand: x1til[v,f] = dinv[v] * relu(bn(sfull[v]*w1[f]+b1[f]))
__global__ void l1_expand_k(const float* __restrict__ sfull, const float* __restrict__ dinv,
                            const float* __restrict__ w1, const float* __restrict__ b1,
                            const float* __restrict__ bg, const float* __restrict__ bb,
                            const float* __restrict__ brm, const float* __restrict__ brv,
                            float* __restrict__ xout) {
    int tid = blockIdx.x * 256 + threadIdx.x;
    if (tid >= N_NODES * HDIM) return;
    int v = tid >> 6;
    int f = tid & 63;
    float sc = bg[f] * rsqrtf(brv[f] + BN_EPS);
    float val = (sfull[v] * w1[f] + b1[f] - brm[f]) * sc + bb[f];
    xout[tid] = dinv[v] * fmaxf(val, 0.f);
}

// ======== Layers 2/3: aggregate pre-scaled rows, then @W + BN + ReLU ========

__global__ __launch_bounds__(256) void agg_gemm_k(
    const float* __restrict__ xin, float* __restrict__ xout,
    const int* __restrict__ ptr, const int* __restrict__ csr,
    const float* __restrict__ dinv, const float* __restrict__ oscale_arr,
    const float* __restrict__ W, const float* __restrict__ bias,
    const float* __restrict__ bg, const float* __restrict__ bb,
    const float* __restrict__ brm, const float* __restrict__ brv) {
    __shared__ float wsh[HDIM * HDIM]; // 16 KB
    __shared__ float sM[HDIM], sC[HDIM];
    int tid = threadIdx.x;
    for (int i = tid; i < HDIM * HDIM; i += 256) wsh[i] = W[i];
    if (tid < HDIM) {
        float sc = bg[tid] * rsqrtf(brv[tid] + BN_EPS);
        sM[tid] = sc;
        sC[tid] = (bias[tid] - brm[tid]) * sc + bb[tid];
    }
    __syncthreads();

    int lane = tid & 63;
    int v = (blockIdx.x << 2) + (tid >> 6);
    if (v >= N_NODES) return;
    int q = lane >> 4;
    int s = lane & 15;

    const float4* __restrict__ xin4 = (const float4*)xin;
    int e0 = ptr[v], e1 = ptr[v + 1];
    float4 acc;
    if (q == 0) {
        acc = xin4[(size_t)v * 16 + s];   // self-loop (pre-scaled row)
    } else {
        acc.x = acc.y = acc.z = acc.w = 0.f;
    }

    for (int e = e0; e < e1; e += 16) {
#pragma unroll
        for (int j = 0; j < 4; j++) {
            int ee = e + j * 4 + q;
            if (ee < e1) {
                int u = csr[ee];                         // 4B, broadcast in quarter
                float4 row = xin4[(size_t)u * 16 + s];   // coalesced 16B/lane
                acc.x += row.x; acc.y += row.y;
                acc.z += row.z; acc.w += row.w;
            }
        }
    }

    float a4[4] = {acc.x, acc.y, acc.z, acc.w};
#pragma unroll
    for (int i = 0; i < 4; i++) {
        a4[i] += __shfl_xor(a4[i], 16);
        a4[i] += __shfl_xor(a4[i], 32);
    }

    int f = lane;
    float o = 0.f;
#pragma unroll
    for (int k = 0; k < HDIM; k++) {
        float a = __shfl(a4[k & 3], k >> 2);
        o += a * wsh[(k << 6) + f];
    }
    float dv = dinv[v];
    float osc = oscale_arr ? oscale_arr[v] : 1.f;
    float val = fmaxf(dv * o * sM[f] + sC[f], 0.f);
    xout[(size_t)v * HDIM + f] = osc * val;
}

// ======== Pool (mean/max per graph) + MLP head ========

__device__ inline int lower_bound_i(const int* __restrict__ a, int n, int val) {
    int lo = 0, hi = n;
    while (lo < hi) {
        int mid = (lo + hi) >> 1;
        if (a[mid] < val) lo = mid + 1; else hi = mid;
    }
    return lo;
}

__global__ void pool_mlp_k(const float* __restrict__ x, const int* __restrict__ batch,
                           const float* __restrict__ wl1, const float* __restrict__ bl1,
                           const float* __restrict__ wl2, const float* __restrict__ bl2,
                           const float* __restrict__ bg, const float* __restrict__ bb,
                           const float* __restrict__ brm, const float* __restrict__ brv,
                           float* __restrict__ out) {
    int g = blockIdx.x;
    int tid = threadIdx.x;
    int w = tid >> 6;
    int f = tid & 63;
    int start = lower_bound_i(batch, N_NODES, g);
    int end = lower_bound_i(batch, N_NODES, g + 1);
    float sum = 0.f;
    float mx = -3.402823466e38f;
#pragma unroll 2
    for (int v = start + w; v < end; v += 4) {
        float val = x[(size_t)v * HDIM + f];
        sum += val;
        mx = fmaxf(mx, val);
    }
    __shared__ float ssum[4][HDIM], smax[4][HDIM];
    __shared__ float zs[2 * HDIM];
    ssum[w][f] = sum;
    smax[w][f] = mx;
    __syncthreads();
    if (tid < 64) {
        float sm = ssum[0][f] + ssum[1][f] + ssum[2][f] + ssum[3][f];
        float m = fmaxf(fmaxf(smax[0][f], smax[1][f]), fmaxf(smax[2][f], smax[3][f]));
        float cnt = (float)(end - start);
        zs[f] = sm / fmaxf(cnt, 1.f);
        zs[HDIM + f] = m;
    }
    __syncthreads();
    if (tid >= 64) return;

    float o = bl1[f];
#pragma unroll 8
    for (int k = 0; k < 2 * HDIM; k++) {
        o += zs[k] * wl1[k * HDIM + f];
    }
    float sc = bg[f] * rsqrtf(brv[f] + BN_EPS);
    o = fmaxf((o - brm[f]) * sc + bb[f], 0.f);

    float p0 = o * wl2[f * 2 + 0];
    float p1 = o * wl2[f * 2 + 1];
    for (int off = 32; off > 0; off >>= 1) {
        p0 += __shfl_down(p0, off);
        p1 += __shfl_down(p1, off);
    }
    if (f == 0) {
        out[g * 2 + 0] = p0 + bl2[0];
        out[g * 2 + 1] = p1 + bl2[1];
    }
}

// ======== launch ========

extern "C" void kernel_launch(void* const* d_in, const int* in_sizes, int n_in,
                              void* d_out, int out_size, void* d_ws, size_t ws_size,
                              hipStream_t stream) {
    const float* x    = (const float*)d_in[0];
    const int* src    = (const int*)d_in[1];
    const int* dst    = (const int*)d_in[2];
    const int* batch  = (const int*)d_in[3];
    const float* w1   = (const float*)d_in[4];
    const float* b1   = (const float*)d_in[5];
    const float* w2   = (const float*)d_in[6];
    const float* b2   = (const float*)d_in[7];
    const float* w3   = (const float*)d_in[8];
    const float* b3   = (const float*)d_in[9];
    const float* wl1  = (const float*)d_in[10];
    const float* bl1  = (const float*)d_in[11];
    const float* wl2  = (const float*)d_in[12];
    const float* bl2  = (const float*)d_in[13];
    const float* bn1g = (const float*)d_in[14];
    const float* bn1b = (const float*)d_in[15];
    const float* bn1rm = (const float*)d_in[16];
    const float* bn1rv = (const float*)d_in[17];
    const float* bn2g = (const float*)d_in[18];
    const float* bn2b = (const float*)d_in[19];
    const float* bn2rm = (const float*)d_in[20];
    const float* bn2rv = (const float*)d_in[21];
    const float* bn3g = (const float*)d_in[22];
    const float* bn3b = (const float*)d_in[23];
    const float* bn3rm = (const float*)d_in[24];
    const float* bn3rv = (const float*)d_in[25];
    const float* bnlg = (const float*)d_in[26];
    const float* bnlb = (const float*)d_in[27];
    const float* bnlrm = (const float*)d_in[28];
    const float* bnlrv = (const float*)d_in[29];
    float* out = (float*)d_out;

    char* ws = (char*)d_ws;
    size_t off = 0;
    auto alloc = [&](size_t bytes) -> char* {
        off = (off + 255) & ~(size_t)255;
        char* p = ws + off;
        off += bytes;
        return p;
    };
    int*   histT    = (int*)alloc((size_t)NBUCKET * NCHUNK * 4);
    int*   scannedT = (int*)alloc((size_t)NBUCKET * NCHUNK * 4);
    int*   bbase    = (int*)alloc((NBUCKET + 1) * 4);
    int*   staging  = (int*)alloc((size_t)E_EDGES * 4);
    int*   csr      = (int*)alloc((size_t)E_EDGES * 4);
    int*   ptr      = (int*)alloc(((size_t)N_NODES + 1) * 4);
    float* dinv     = (float*)alloc((size_t)N_NODES * 4);
    float* xtil     = (float*)alloc((size_t)N_NODES * 4);
    float* sfull    = (float*)alloc((size_t)N_NODES * 4);
    float* xa       = (float*)alloc((size_t)N_NODES * HDIM * 4);
    float* xb       = (float*)alloc((size_t)N_NODES * HDIM * 4);
    if (off > ws_size) {
        fprintf(stderr, "kernel_launch: ws too small (%zu > %zu)\n", off, ws_size);
    }

    const int NB_NH = (N_NODES * HDIM + 255) / 256;
    const int NB_WV = (N_NODES + 3) / 4;

    hist_k<<<NCHUNK, 256, 0, stream>>>(dst, histT);
    scanA_k<<<1, 512, 0, stream>>>(histT, bbase);
    scanB_k<<<NBUCKET, NCHUNK, 0, stream>>>(histT, bbase, scannedT);
    scatter_k<<<NCHUNK, 256, 0, stream>>>(src, dst, scannedT, staging);
    nodeptr_k<<<NBUCKET, 256, 0, stream>>>(staging, bbase, x, ptr, dinv, xtil);
    csr_l1_k<<<NBUCKET, 256, 0, stream>>>(staging, ptr, bbase, dinv, xtil, x, csr, sfull);

    l1_expand_k<<<NB_NH, 256, 0, stream>>>(sfull, dinv, w1, b1,
                                           bn1g, bn1b, bn1rm, bn1rv, xa);

    agg_gemm_k<<<NB_WV, 256, 0, stream>>>(xa, xb, ptr, csr, dinv, dinv,
                                          w2, b2, bn2g, bn2b, bn2rm, bn2rv);
    agg_gemm_k<<<NB_WV, 256, 0, stream>>>(xb, xa, ptr, csr, dinv, nullptr,
                                          w3, b3, bn3g, bn3b, bn3rm, bn3rv);

    pool_mlp_k<<<N_GRAPH, 256, 0, stream>>>(xa, batch, wl1, bl1, wl2, bl2,
                                            bnlg, bnlb, bnlrm, bnlrv, out);
}

// Round 5
// 515.233 us; speedup vs baseline: 4.0294x; 1.7228x over previous
//
#include <hip/hip_runtime.h>
#include <hip/hip_bf16.h>
#include <cstdio>

#define N_NODES 100000
#define E_EDGES 3200000
#define N_GRAPH 512
#define HDIM 64
#define BN_EPS 1e-5f
#define NBUCKET ((N_NODES + 255) / 256)   // 391 buckets of 256 nodes
#define NCHUNK 256                        // edge chunks (radix partition)
#define CHUNK ((E_EDGES + NCHUNK - 1) / NCHUNK) // 12500 edges/chunk
#define SORT_CAP 12288                    // per-bucket LDS entries (mean 8192, max ~8600)

typedef _Float16 f16;
typedef _Float16 half8 __attribute__((ext_vector_type(8)));

// ======== counter-free radix partition of edges by dst>>8 ========

__global__ __launch_bounds__(256) void hist_k(const int* __restrict__ dst,
                                              int* __restrict__ histT) {
    __shared__ int h[NBUCKET];
    int c = blockIdx.x, t = threadIdx.x;
    for (int i = t; i < NBUCKET; i += 256) h[i] = 0;
    __syncthreads();
    int e0 = c * CHUNK;
    int e1 = min(e0 + CHUNK, E_EDGES);
    for (int e = e0 + t; e < e1; e += 256)
        atomicAdd(&h[dst[e] >> 8], 1);
    __syncthreads();
    for (int i = t; i < NBUCKET; i += 256) histT[i * NCHUNK + c] = h[i];
}

__global__ void scanA_k(const int* __restrict__ histT, int* __restrict__ bucket_base) {
    __shared__ int sh[512];
    int t = threadIdx.x;
    int sum = 0;
    if (t < NBUCKET) {
        const int* row = histT + t * NCHUNK;
        for (int c = 0; c < NCHUNK; c++) sum += row[c];
    }
    sh[t] = sum;
    __syncthreads();
    for (int off = 1; off < 512; off <<= 1) {
        int add = (t >= off) ? sh[t - off] : 0;
        __syncthreads();
        sh[t] += add;
        __syncthreads();
    }
    if (t < NBUCKET) bucket_base[t] = sh[t] - sum;
    if (t == 0) bucket_base[NBUCKET] = E_EDGES;
}

__global__ __launch_bounds__(NCHUNK) void scanB_k(const int* __restrict__ histT,
                                                  const int* __restrict__ bucket_base,
                                                  int* __restrict__ scannedT) {
    __shared__ int sh[NCHUNK];
    int b = blockIdx.x, t = threadIdx.x;
    int v = histT[b * NCHUNK + t];
    sh[t] = v;
    __syncthreads();
    for (int off = 1; off < NCHUNK; off <<= 1) {
        int add = (t >= off) ? sh[t - off] : 0;
        __syncthreads();
        sh[t] += add;
        __syncthreads();
    }
    scannedT[b * NCHUNK + t] = bucket_base[b] + sh[t] - v;
}

__global__ __launch_bounds__(256) void scatter_k(const int* __restrict__ src,
                                                 const int* __restrict__ dst,
                                                 const int* __restrict__ scannedT,
                                                 int* __restrict__ staging) {
    __shared__ int lcnt[NBUCKET];
    int c = blockIdx.x, t = threadIdx.x;
    for (int i = t; i < NBUCKET; i += 256) lcnt[i] = scannedT[i * NCHUNK + c];
    __syncthreads();
    int e0 = c * CHUNK;
    int e1 = min(e0 + CHUNK, E_EDGES);
    for (int e = e0 + t; e < e1; e += 256) {
        int v = dst[e], u = src[e];
        int pos = atomicAdd(&lcnt[v >> 8], 1);       // LDS atomic
        staging[pos] = u | ((v & 255) << 17);        // 4B, ~128B runs per bucket
    }
}

// ======== per-bucket: node degrees -> ptr/dinv/xtil ========

__global__ __launch_bounds__(256) void nodeptr_k(const int* __restrict__ staging,
                                                 const int* __restrict__ bucket_base,
                                                 const float* __restrict__ x,
                                                 int* __restrict__ ptr,
                                                 float* __restrict__ dinv,
                                                 float* __restrict__ xtil) {
    __shared__ int hn[256];
    __shared__ int sc[256];
    int t = threadIdx.x, b = blockIdx.x;
    int v0 = b << 8;
    int p0 = bucket_base[b], p1 = bucket_base[b + 1];
    hn[t] = 0;
    __syncthreads();
    int cnt = p1 - p0;
    for (int i = t; i < cnt; i += 256)
        atomicAdd(&hn[staging[p0 + i] >> 17], 1);
    __syncthreads();
    int my = hn[t];
    sc[t] = my;
    __syncthreads();
    for (int off = 1; off < 256; off <<= 1) {
        int add = (t >= off) ? sc[t - off] : 0;
        __syncthreads();
        sc[t] += add;
        __syncthreads();
    }
    int v = v0 + t;
    if (v < N_NODES) {
        ptr[v] = p0 + sc[t] - my;
        float dv = rsqrtf((float)(my + 1));
        dinv[v] = dv;
        xtil[v] = dv * x[v];
    }
    if (b == NBUCKET - 1 && t == 0) ptr[N_NODES] = E_EDGES;
}

// ======== per-bucket: grouped CSR write + fused layer-1 scalar aggregation ========
// Emits pairs[v] = {sfull[v], dinv[v]} -- the entire layer-1 state per node.

__global__ __launch_bounds__(256) void csr_l1_k(const int* __restrict__ staging,
                                                const int* __restrict__ ptr,
                                                const int* __restrict__ bucket_base,
                                                const float* __restrict__ dinv,
                                                const float* __restrict__ xtil,
                                                const float* __restrict__ x,
                                                int* __restrict__ csr,
                                                float2* __restrict__ pairs) {
    __shared__ int lbase[257];
    __shared__ int lcnt[256];
    __shared__ int lds_u[SORT_CAP];
    int t = threadIdx.x, b = blockIdx.x;
    int v0 = b << 8;
    int p0 = bucket_base[b];
    for (int i = t; i < 257; i += 256) {
        int vv = v0 + i;
        lbase[i] = ((vv < N_NODES) ? ptr[vv] : E_EDGES) - p0;
    }
    lcnt[t] = 0;
    __syncthreads();
    int cnt = lbase[256];
    for (int i = t; i < cnt; i += 256) {
        int packed = staging[p0 + i];
        int u = packed & 0x1FFFF;
        int vl = packed >> 17;
        int r = atomicAdd(&lcnt[vl], 1);
        int pos = lbase[vl] + r;
        if (pos < SORT_CAP) lds_u[pos] = u;
        else csr[p0 + pos] = u;
    }
    __syncthreads();
    int lim = (cnt < SORT_CAP) ? cnt : SORT_CAP;
    for (int i = t; i < lim; i += 256) csr[p0 + i] = lds_u[i];
    __syncthreads();
    int v = v0 + t;
    if (v < N_NODES) {
        int j0 = lbase[t], j1 = lbase[t + 1];
        float s = 0.f;
        for (int j = j0; j < j1; j++) {
            int u = (j < SORT_CAP) ? lds_u[j] : csr[p0 + j];
            s += xtil[u];
        }
        float dv = dinv[v];
        pairs[v] = make_float2(dv * s + dv * dv * x[v], dv);
    }
}

// ======== Layer 2: scalar-pair gather (800KB L2-resident) + @W2 + BN + ReLU ========
// x1til[u,f] = dinv_u * relu(m1[f]*sfull_u + c1[f]) reconstructed in-register.
// Wave per node; octet o=lane>>3 handles edge slot, s=lane&7 -> features s*8..s*8+7.

__global__ __launch_bounds__(256) void agg_l2_k(
    const float2* __restrict__ pairs, f16* __restrict__ xout,
    const int* __restrict__ ptr, const int* __restrict__ csr,
    const float* __restrict__ w1, const float* __restrict__ b1,
    const float* __restrict__ bg1, const float* __restrict__ bb1,
    const float* __restrict__ brm1, const float* __restrict__ brv1,
    const float* __restrict__ W2, const float* __restrict__ bias2,
    const float* __restrict__ bg2, const float* __restrict__ bb2,
    const float* __restrict__ brm2, const float* __restrict__ brv2) {
    __shared__ float wsh[HDIM * HDIM];
    __shared__ float sM[HDIM], sC[HDIM];
    int tid = threadIdx.x;
    for (int i = tid; i < HDIM * HDIM; i += 256) wsh[i] = W2[i];
    if (tid < HDIM) {
        float sc = bg2[tid] * rsqrtf(brv2[tid] + BN_EPS);
        sM[tid] = sc;
        sC[tid] = (bias2[tid] - brm2[tid]) * sc + bb2[tid];
    }
    __syncthreads();

    int lane = tid & 63;
    int v = (blockIdx.x << 2) + (tid >> 6);
    if (v >= N_NODES) return;
    int o = lane >> 3, s = lane & 7;

    float m1[8], c1[8];  // per-lane layer-1 affine for features f = s*8+i
#pragma unroll
    for (int i = 0; i < 8; i++) {
        int f = s * 8 + i;
        float sc1 = bg1[f] * rsqrtf(brv1[f] + BN_EPS);
        m1[i] = sc1 * w1[f];
        c1[i] = (b1[f] - brm1[f]) * sc1 + bb1[f];
    }

    int e0 = ptr[v], e1 = ptr[v + 1];
    float2 pv = pairs[v];
    float acc[8];
    {
        float cf = (o == 0) ? pv.y : 0.f;   // self-loop, once
#pragma unroll
        for (int i = 0; i < 8; i++)
            acc[i] = cf * fmaxf(m1[i] * pv.x + c1[i], 0.f);
    }
    for (int e = e0; e < e1; e += 16) {
#pragma unroll
        for (int j = 0; j < 2; j++) {
            int ee = e + j * 8 + o;
            int eidx = (ee < e1) ? ee : (e1 - 1);  // clamp: hits same line
            int u = csr[eidx];
            float2 p = pairs[u];                   // 8B gather, L2-resident
            float cf = (ee < e1) ? p.y : 0.f;
#pragma unroll
            for (int i = 0; i < 8; i++)
                acc[i] += cf * fmaxf(m1[i] * p.x + c1[i], 0.f);
        }
    }
#pragma unroll
    for (int i = 0; i < 8; i++) {
        acc[i] += __shfl_xor(acc[i], 8);
        acc[i] += __shfl_xor(acc[i], 16);
        acc[i] += __shfl_xor(acc[i], 32);
    }
    int f = lane;
    float ov = 0.f;
#pragma unroll
    for (int k = 0; k < HDIM; k++) {
        float a = __shfl(acc[k & 7], k >> 3);  // feature k at lane k>>3, idx k&7
        ov += a * wsh[(k << 6) + f];
    }
    float val = fmaxf(pv.y * ov * sM[f] + sC[f], 0.f);
    xout[(size_t)v * HDIM + f] = (f16)(pv.y * val);  // pre-scaled for layer 3
}

// ======== Layer 3: fp16 row gather (8 rows per wave-load) + @W3 + BN + ReLU ========

__global__ __launch_bounds__(256, 8) void agg_gemm_k(
    const f16* __restrict__ xin, f16* __restrict__ xout,
    const int* __restrict__ ptr, const int* __restrict__ csr,
    const float2* __restrict__ pairs,
    const float* __restrict__ W, const float* __restrict__ bias,
    const float* __restrict__ bg, const float* __restrict__ bb,
    const float* __restrict__ brm, const float* __restrict__ brv) {
    __shared__ float wsh[HDIM * HDIM];
    __shared__ float sM[HDIM], sC[HDIM];
    int tid = threadIdx.x;
    for (int i = tid; i < HDIM * HDIM; i += 256) wsh[i] = W[i];
    if (tid < HDIM) {
        float sc = bg[tid] * rsqrtf(brv[tid] + BN_EPS);
        sM[tid] = sc;
        sC[tid] = (bias[tid] - brm[tid]) * sc + bb[tid];
    }
    __syncthreads();

    int lane = tid & 63;
    int v = (blockIdx.x << 2) + (tid >> 6);
    if (v >= N_NODES) return;
    int o = lane >> 3, s = lane & 7;

    const half8* __restrict__ xin8 = (const half8*)xin;
    int e0 = ptr[v], e1 = ptr[v + 1];
    float acc[8];
    {
        half8 r = xin8[(size_t)v * 8 + s];     // self-loop row (broadcast load)
        float cf = (o == 0) ? 1.f : 0.f;
#pragma unroll
        for (int i = 0; i < 8; i++) acc[i] = cf * (float)r[i];
    }
    for (int e = e0; e < e1; e += 32) {
#pragma unroll
        for (int j = 0; j < 4; j++) {
            int ee = e + j * 8 + o;
            int eidx = (ee < e1) ? ee : (e1 - 1);  // clamp: same line, no extra traffic
            int u = csr[eidx];
            half8 r = xin8[(size_t)u * 8 + s];     // 16B/lane, 8 rows per wave-load
            float cf = (ee < e1) ? 1.f : 0.f;
#pragma unroll
            for (int i = 0; i < 8; i++) acc[i] += cf * (float)r[i];
        }
    }
#pragma unroll
    for (int i = 0; i < 8; i++) {
        acc[i] += __shfl_xor(acc[i], 8);
        acc[i] += __shfl_xor(acc[i], 16);
        acc[i] += __shfl_xor(acc[i], 32);
    }
    int f = lane;
    float ov = 0.f;
#pragma unroll
    for (int k = 0; k < HDIM; k++) {
        float a = __shfl(acc[k & 7], k >> 3);
        ov += a * wsh[(k << 6) + f];
    }
    float dv = pairs[v].y;
    float val = fmaxf(dv * ov * sM[f] + sC[f], 0.f);
    xout[(size_t)v * HDIM + f] = (f16)val;
}

// ======== Pool (mean/max per graph) + MLP head ========

__device__ inline int lower_bound_i(const int* __restrict__ a, int n, int val) {
    int lo = 0, hi = n;
    while (lo < hi) {
        int mid = (lo + hi) >> 1;
        if (a[mid] < val) lo = mid + 1; else hi = mid;
    }
    return lo;
}

__global__ void pool_mlp_k(const f16* __restrict__ x, const int* __restrict__ batch,
                           const float* __restrict__ wl1, const float* __restrict__ bl1,
                           const float* __restrict__ wl2, const float* __restrict__ bl2,
                           const float* __restrict__ bg, const float* __restrict__ bb,
                           const float* __restrict__ brm, const float* __restrict__ brv,
                           float* __restrict__ out) {
    int g = blockIdx.x;
    int tid = threadIdx.x;
    int w = tid >> 6;
    int f = tid & 63;
    int start = lower_bound_i(batch, N_NODES, g);
    int end = lower_bound_i(batch, N_NODES, g + 1);
    float sum = 0.f;
    float mx = -3.402823466e38f;
#pragma unroll 2
    for (int v = start + w; v < end; v += 4) {
        float val = (float)x[(size_t)v * HDIM + f];
        sum += val;
        mx = fmaxf(mx, val);
    }
    __shared__ float ssum[4][HDIM], smax[4][HDIM];
    __shared__ float zs[2 * HDIM];
    ssum[w][f] = sum;
    smax[w][f] = mx;
    __syncthreads();
    if (tid < 64) {
        float sm = ssum[0][f] + ssum[1][f] + ssum[2][f] + ssum[3][f];
        float m = fmaxf(fmaxf(smax[0][f], smax[1][f]), fmaxf(smax[2][f], smax[3][f]));
        float cnt = (float)(end - start);
        zs[f] = sm / fmaxf(cnt, 1.f);
        zs[HDIM + f] = m;
    }
    __syncthreads();
    if (tid >= 64) return;

    float o = bl1[f];
#pragma unroll 8
    for (int k = 0; k < 2 * HDIM; k++) {
        o += zs[k] * wl1[k * HDIM + f];
    }
    float sc = bg[f] * rsqrtf(brv[f] + BN_EPS);
    o = fmaxf((o - brm[f]) * sc + bb[f], 0.f);

    float p0 = o * wl2[f * 2 + 0];
    float p1 = o * wl2[f * 2 + 1];
    for (int off = 32; off > 0; off >>= 1) {
        p0 += __shfl_down(p0, off);
        p1 += __shfl_down(p1, off);
    }
    if (f == 0) {
        out[g * 2 + 0] = p0 + bl2[0];
        out[g * 2 + 1] = p1 + bl2[1];
    }
}

// ======== launch ========

extern "C" void kernel_launch(void* const* d_in, const int* in_sizes, int n_in,
                              void* d_out, int out_size, void* d_ws, size_t ws_size,
                              hipStream_t stream) {
    const float* x    = (const float*)d_in[0];
    const int* src    = (const int*)d_in[1];
    const int* dst    = (const int*)d_in[2];
    const int* batch  = (const int*)d_in[3];
    const float* w1   = (const float*)d_in[4];
    const float* b1   = (const float*)d_in[5];
    const float* w2   = (const float*)d_in[6];
    const float* b2   = (const float*)d_in[7];
    const float* w3   = (const float*)d_in[8];
    const float* b3   = (const float*)d_in[9];
    const float* wl1  = (const float*)d_in[10];
    const float* bl1  = (const float*)d_in[11];
    const float* wl2  = (const float*)d_in[12];
    const float* bl2  = (const float*)d_in[13];
    const float* bn1g = (const float*)d_in[14];
    const float* bn1b = (const float*)d_in[15];
    const float* bn1rm = (const float*)d_in[16];
    const float* bn1rv = (const float*)d_in[17];
    const float* bn2g = (const float*)d_in[18];
    const float* bn2b = (const float*)d_in[19];
    const float* bn2rm = (const float*)d_in[20];
    const float* bn2rv = (const float*)d_in[21];
    const float* bn3g = (const float*)d_in[22];
    const float* bn3b = (const float*)d_in[23];
    const float* bn3rm = (const float*)d_in[24];
    const float* bn3rv = (const float*)d_in[25];
    const float* bnlg = (const float*)d_in[26];
    const float* bnlb = (const float*)d_in[27];
    const float* bnlrm = (const float*)d_in[28];
    const float* bnlrv = (const float*)d_in[29];
    float* out = (float*)d_out;

    char* ws = (char*)d_ws;
    size_t off = 0;
    auto alloc = [&](size_t bytes) -> char* {
        off = (off + 255) & ~(size_t)255;
        char* p = ws + off;
        off += bytes;
        return p;
    };
    int*    histT    = (int*)alloc((size_t)NBUCKET * NCHUNK * 4);
    int*    scannedT = (int*)alloc((size_t)NBUCKET * NCHUNK * 4);
    int*    bbase    = (int*)alloc((NBUCKET + 1) * 4);
    int*    staging  = (int*)alloc((size_t)E_EDGES * 4);
    int*    csr      = (int*)alloc((size_t)E_EDGES * 4);
    int*    ptr      = (int*)alloc(((size_t)N_NODES + 1) * 4);
    float*  dinv     = (float*)alloc((size_t)N_NODES * 4);
    float*  xtil     = (float*)alloc((size_t)N_NODES * 4);
    float2* pairs    = (float2*)alloc((size_t)N_NODES * 8);
    f16*    xa       = (f16*)alloc((size_t)N_NODES * HDIM * 2);
    f16*    xb       = (f16*)alloc((size_t)N_NODES * HDIM * 2);
    if (off > ws_size) {
        fprintf(stderr, "kernel_launch: ws too small (%zu > %zu)\n", off, ws_size);
    }

    const int NB_WV = (N_NODES + 3) / 4;

    hist_k<<<NCHUNK, 256, 0, stream>>>(dst, histT);
    scanA_k<<<1, 512, 0, stream>>>(histT, bbase);
    scanB_k<<<NBUCKET, NCHUNK, 0, stream>>>(histT, bbase, scannedT);
    scatter_k<<<NCHUNK, 256, 0, stream>>>(src, dst, scannedT, staging);
    nodeptr_k<<<NBUCKET, 256, 0, stream>>>(staging, bbase, x, ptr, dinv, xtil);
    csr_l1_k<<<NBUCKET, 256, 0, stream>>>(staging, ptr, bbase, dinv, xtil, x, csr, pairs);

    agg_l2_k<<<NB_WV, 256, 0, stream>>>(pairs, xb, ptr, csr,
                                        w1, b1, bn1g, bn1b, bn1rm, bn1rv,
                                        w2, b2, bn2g, bn2b, bn2rm, bn2rv);
    agg_gemm_k<<<NB_WV, 256, 0, stream>>>(xb, xa, ptr, csr, pairs,
                                          w3, b3, bn3g, bn3b, bn3rm, bn3rv);

    pool_mlp_k<<<N_GRAPH, 256, 0, stream>>>(xa, batch, wl1, bl1, wl2, bl2,
                                            bnlg, bnlb, bnlrm, bnlrv, out);
}